// Round 8
// baseline (123.786 us; speedup 1.0000x reference)
//
#include <hip/hip_runtime.h>
#include <math.h>

// TripletLoss round 13: un-bundled best-of — round-9 prep/histscan structure
// (measured good) + round-12 dist algebra (negated-A MFMA epilogue fusion,
// Sa via rowsum-dot) + dist register diet for 4 blocks/CU (tail-free grid).
//
// Pipeline: histscan(1 blk, zero-inits + publishes hist/cstart/coffset)
//           -> prep (bf16 convert, class-sorted chunk-major scatter, rowsum)
//           -> dist (MFMA Gram, acc seeded with u directly from memory)
//           -> combine (per-row loss, Sa = rowsum.x_j, last-block final).
//
// dist: acc[0] loaded straight from upk (C-init = u values), acc[1] copied;
// A read from NEGATED bf16 copy -> MFMA computes v = u - x_i.x_j directly;
// fast tile (~97%, class-sorted) epilogue is min3 chains only. Slow tiles
// re-read upk for tags (L2-hot, block-uniform branch).
// Chunk-major Xbf: 1 KB coalesced fragment loads, no LDS staging, no K-loop
// barriers, slice==XCD (bx&7).

#define NROWS 8192
#define MARGIN_F 0.3f

typedef short bf16x8 __attribute__((ext_vector_type(8)));
typedef float f32x16 __attribute__((ext_vector_type(16)));
union U4B { uint4 u; bf16x8 h; };

__device__ __forceinline__ unsigned short f2bf(float x) {
    unsigned u = __float_as_uint(x);
    return (unsigned short)((u + 0x7fffu + ((u >> 16) & 1u)) >> 16);
}
__device__ __forceinline__ float bflo(unsigned u) { return __uint_as_float(u << 16); }
__device__ __forceinline__ float bfhi(unsigned u) { return __uint_as_float(u & 0xffff0000u); }

// ---- K0: hist + scan + zero-init (single block) ----
__global__ __launch_bounds__(256) void histscan_kernel(const int* __restrict__ tgt,
                                                       int* __restrict__ hist,
                                                       int* __restrict__ cstart,
                                                       int* __restrict__ coffset,
                                                       float* __restrict__ S_class,
                                                       float* __restrict__ rowsum,
                                                       int* __restrict__ done) {
    __shared__ int h[256];
    __shared__ int wsum[4];
    int t = threadIdx.x;
    h[t] = 0;
    S_class[t] = 0.0f;
    if (t < 128) rowsum[t] = 0.0f;
    if (t == 0) *done = 0;
    __syncthreads();
    const int4* t4 = (const int4*)tgt;
    for (int i = t; i < NROWS / 4; i += 256) {
        int4 v = t4[i];
        atomicAdd(&h[v.x], 1);
        atomicAdd(&h[v.y], 1);
        atomicAdd(&h[v.z], 1);
        atomicAdd(&h[v.w], 1);
    }
    __syncthreads();
    int hv = h[t];
    hist[t] = hv;
    int x = hv;
    #pragma unroll
    for (int d = 1; d < 64; d <<= 1) {
        int y = __shfl_up(x, d, 64);
        if ((t & 63) >= d) x += y;
    }
    if ((t & 63) == 63) wsum[t >> 6] = x;
    __syncthreads();
    int off = 0;
    for (int i = 0; i < (t >> 6); ++i) off += wsum[i];
    int excl = off + x - hv;        // exclusive prefix
    cstart[t] = excl;
    coffset[t] = excl;
    if (t == 255) cstart[256] = NROWS;
}

// ---- K1: bf16 convert + class-sorted chunk-major scatter (pos+neg) ----
__global__ __launch_bounds__(256) void prep_kernel(const float* __restrict__ X,
                                                   const int* __restrict__ tgt,
                                                   float* __restrict__ sq,
                                                   float* __restrict__ upk,
                                                   unsigned int* __restrict__ Xbf,
                                                   unsigned int* __restrict__ Xbfn,
                                                   int* __restrict__ coffset,
                                                   float* __restrict__ S_class,
                                                   float* __restrict__ bsum,
                                                   float* __restrict__ rowsum) {
    __shared__ float rsm[4][128];
    __shared__ float bs[4];
    int tid = threadIdx.x, w = tid >> 6, l = tid & 63;
    int bx = blockIdx.x;
    int row0 = bx * 32 + w * 8;

    unsigned h2s[8];
    float s8[8];
    int c8[8];
    float rsx = 0.0f, rsy = 0.0f, rs = 0.0f;

    // phase A: convert, row norms, rowsum partials
    #pragma unroll
    for (int i = 0; i < 8; ++i) {
        int r = row0 + i;
        float2 v = ((const float2*)X)[(size_t)r * 64 + l];
        unsigned hx = f2bf(v.x), hy = f2bf(v.y);
        h2s[i] = hx | (hy << 16);
        rsx += v.x; rsy += v.y;
        float s = v.x * v.x + v.y * v.y;
        for (int d = 32; d > 0; d >>= 1) s += __shfl_down(s, d, 64);
        if (l == 0) {
            c8[i] = tgt[r];
            s8[i] = s;
            rs += s;
        }
    }
    rsm[w][2 * l] = rsx;
    rsm[w][2 * l + 1] = rsy;
    if (l == 0) bs[w] = rs;
    __syncthreads();
    if (tid < 128)
        atomicAdd(&rowsum[tid], rsm[0][tid] + rsm[1][tid] + rsm[2][tid] + rsm[3][tid]);
    if (tid == 0) bsum[bx] = bs[0] + bs[1] + bs[2] + bs[3];

    // phase B: scatter rows (chunk-major, pos + neg copies)
    #pragma unroll
    for (int i = 0; i < 8; ++i) {
        int pos = 0;
        if (l == 0) {
            int c = c8[i];
            pos = atomicAdd(&coffset[c], 1);   // absolute position
            sq[pos] = s8[i];
            upk[pos] = __uint_as_float((__float_as_uint(0.5f * s8[i]) & 0xffffff00u) | (unsigned)c);
            atomicAdd(&S_class[c], s8[i]);
        }
        pos = __shfl(pos, 0, 64);
        int g = pos >> 5, rr = pos & 31;
        size_t idx = ((size_t)(g * 16 + (l >> 2)) * 32 + rr) * 4 + (l & 3);
        unsigned hh = h2s[i];
        Xbf[idx] = hh;
        Xbfn[idx] = hh ^ 0x80008000u;
    }
}

// ---- K2: MFMA Gram (v = u - x.x via negated A + C-init), column stats ----
__global__ __launch_bounds__(256, 4) void dist_kernel(
        const unsigned short* __restrict__ Xbf, const unsigned short* __restrict__ Xbfn,
        const float* __restrict__ upk, const int* __restrict__ cstart,
        float4* __restrict__ partial, int ns_mask, int jb_shift, int tiles) {
    __shared__ float4 sm[64 * 4];
    const int tid = threadIdx.x;
    const int w = tid >> 6, l = tid & 63, hl = l >> 5, l31 = l & 31;
    const int bx = blockIdx.x;
    const int slice = bx & ns_mask;   // == XCD id for ns=8
    const int jb = bx >> jb_shift;    // 64-col strip
    const int col0 = jb * 64;
    const uint4* Xq = (const uint4*)Xbf;
    const uint4* Xqn = (const uint4*)Xbfn;

    // B fragments (positive copy), 1 KB coalesced per read
    bf16x8 Bf[2][8];
    #pragma unroll
    for (int ct = 0; ct < 2; ++ct) {
        const uint4* bp = Xq + (size_t)(jb * 2 + ct) * 512 + hl * 32 + l31;
        #pragma unroll
        for (int kk = 0; kk < 8; ++kk) {
            U4B tb; tb.u = bp[kk * 64];
            Bf[ct][kk] = tb.h;
        }
    }
    int tjt[2];
    tjt[0] = __float_as_int(upk[col0 + l31]) & 0xff;
    tjt[1] = __float_as_int(upk[col0 + 32 + l31]) & 0xff;
    const int c_first = __float_as_int(upk[col0]) & 0xff;
    const int c_last  = __float_as_int(upk[col0 + 63]) & 0xff;
    const int U0 = cstart[c_first];
    const int U1 = cstart[c_last + 1];

    float Ss[2] = {0.f, 0.f};
    float Mp[2] = {-INFINITY, -INFINITY};
    float Mn[2] = { INFINITY,  INFINITY};
    const int row_base = slice * tiles * 128;

    for (int t = 0; t < tiles; ++t) {
        const int i0 = row_base + t * 128;

        // C-init loaded straight into acc[0] (u values), acc[1] = copy
        f32x16 acc[2];
        const float4* up = (const float4*)(upk + i0 + w * 32 + 4 * hl);
        #pragma unroll
        for (int g = 0; g < 4; ++g) {
            float4 u4 = up[g * 2];
            acc[0][g * 4 + 0] = u4.x; acc[0][g * 4 + 1] = u4.y;
            acc[0][g * 4 + 2] = u4.z; acc[0][g * 4 + 3] = u4.w;
        }
        acc[1] = acc[0];

        // negated A makes MFMA compute v = u - x_i.x_j
        const uint4* ap = Xqn + ((size_t)(i0 >> 5) + w) * 512 + hl * 32 + l31;
        #pragma unroll
        for (int kk = 0; kk < 8; ++kk) {
            U4B a; a.u = ap[kk * 64];
            acc[0] = __builtin_amdgcn_mfma_f32_32x32x16_bf16(a.h, Bf[0][kk], acc[0], 0, 0, 0);
            acc[1] = __builtin_amdgcn_mfma_f32_32x32x16_bf16(a.h, Bf[1][kk], acc[1], 0, 0, 0);
        }

        if (i0 < U1 && i0 + 128 > U0) {
            // slow tile (block-uniform, ~1-2 per block): re-read u for tags
            float ur[16];
            #pragma unroll
            for (int g = 0; g < 4; ++g) {
                float4 u4 = up[g * 2];
                ur[g * 4 + 0] = u4.x; ur[g * 4 + 1] = u4.y;
                ur[g * 4 + 2] = u4.z; ur[g * 4 + 3] = u4.w;
            }
            #pragma unroll
            for (int ct = 0; ct < 2; ++ct) {
                const int tt = tjt[ct];
                #pragma unroll
                for (int r = 0; r < 16; ++r) {
                    float v = acc[ct][r];
                    bool same = ((__float_as_int(ur[r]) & 0xff) == tt);
                    float a = ur[r] - v;
                    Ss[ct] += same ? a : 0.0f;
                    Mp[ct] = fmaxf(Mp[ct], same ? v : -INFINITY);
                    Mn[ct] = same ? Mn[ct] : fminf(Mn[ct], v);
                }
            }
        } else {
            // fast tile: pure negatives -- min3 chains only
            #pragma unroll
            for (int ct = 0; ct < 2; ++ct) {
                #pragma unroll
                for (int r = 0; r < 16; r += 2)
                    Mn[ct] = fminf(fminf(acc[ct][r], acc[ct][r + 1]), Mn[ct]);
            }
        }
    }

    // merge half-lanes, then 4 waves via LDS, write coalesced partial
    #pragma unroll
    for (int ct = 0; ct < 2; ++ct) {
        Ss[ct] += __shfl_xor(Ss[ct], 32, 64);
        Mp[ct] = fmaxf(Mp[ct], __shfl_xor(Mp[ct], 32, 64));
        Mn[ct] = fminf(Mn[ct], __shfl_xor(Mn[ct], 32, 64));
    }
    if (l < 32) {
        #pragma unroll
        for (int ct = 0; ct < 2; ++ct)
            sm[(ct * 32 + l31) * 4 + w] = make_float4(Ss[ct], Mp[ct], Mn[ct], 0.0f);
    }
    __syncthreads();
    if (tid < 64) {
        float4 a = sm[tid * 4 + 0], b = sm[tid * 4 + 1];
        float4 c2 = sm[tid * 4 + 2], d = sm[tid * 4 + 3];
        float4 o;
        o.x = a.x + b.x + c2.x + d.x;
        o.y = fmaxf(fmaxf(a.y, b.y), fmaxf(c2.y, d.y));
        o.z = fminf(fminf(a.z, b.z), fminf(c2.z, d.z));
        o.w = 0.0f;
        partial[(size_t)slice * NROWS + col0 + tid] = o;
    }
}

// ---- K3: per-row loss (Sa via rowsum dot) + last-block final reduction ----
__global__ __launch_bounds__(256) void combine_kernel(
        const float* __restrict__ sq, const float* __restrict__ upk,
        const unsigned int* __restrict__ Xbf,
        const int* __restrict__ hist, const float* __restrict__ S_class,
        const float* __restrict__ bsum, const float* __restrict__ rowsum,
        const float4* __restrict__ partial,
        float* __restrict__ blocksum, int* __restrict__ done,
        float* __restrict__ out, int ns) {
    __shared__ float red[4];
    __shared__ float hs[4];
    __shared__ float rsl[128];
    __shared__ int lastflag;
    int tid = threadIdx.x, l = tid & 63, w = tid >> 6;

    if (tid < 128) rsl[tid] = rowsum[tid];

    // S_all = sum of prep's 256 per-block sums
    float b = bsum[tid];
    for (int d = 32; d > 0; d >>= 1) b += __shfl_down(b, d, 64);
    if (l == 0) red[w] = b;
    __syncthreads();
    float S_all = red[0] + red[1] + red[2] + red[3];

    int j = blockIdx.x * 256 + tid;
    float Ss = 0.f, Mp = -INFINITY, Mn = INFINITY;
    for (int s = 0; s < ns; ++s) {
        float4 p = partial[(size_t)s * NROWS + j];
        Ss += p.x;
        Mp = fmaxf(Mp, p.y); Mn = fminf(Mn, p.z);
    }

    // Sa_j = rowsum . x_j  (chunk-major bf16 row, coalesced across lanes)
    float sa = 0.0f;
    {
        const uint4* Xq = (const uint4*)Xbf;
        int g = j >> 5, rr = j & 31;
        #pragma unroll
        for (int c16 = 0; c16 < 16; ++c16) {
            uint4 q = Xq[((size_t)(g * 16 + c16)) * 32 + rr];
            int k0 = c16 * 8;
            sa = fmaf(bflo(q.x), rsl[k0 + 0], sa);
            sa = fmaf(bfhi(q.x), rsl[k0 + 1], sa);
            sa = fmaf(bflo(q.y), rsl[k0 + 2], sa);
            sa = fmaf(bfhi(q.y), rsl[k0 + 3], sa);
            sa = fmaf(bflo(q.z), rsl[k0 + 4], sa);
            sa = fmaf(bfhi(q.z), rsl[k0 + 5], sa);
            sa = fmaf(bflo(q.w), rsl[k0 + 6], sa);
            sa = fmaf(bfhi(q.w), rsl[k0 + 7], sa);
        }
    }

    float sqj = sq[j];
    int c = __float_as_int(upk[j]) & 0xff;
    float cnt = (float)hist[c];
    float sumall = (float)NROWS * sqj + S_all - 2.0f * sa;
    float sump = cnt * sqj + S_class[c] - 2.0f * Ss;
    float sumn = sumall - sump;
    float sigp = sump / (cnt - 1.0f);
    float sign_ = sumn / ((float)NROWS - cnt);
    float ap = (sqj + 2.0f * Mp) / sigp + 0.5f * __logf(sigp);
    float an = (sqj + 2.0f * Mn) / sign_ + 0.5f * __logf(sign_);
    float h = fmaxf(ap - an + MARGIN_F, 0.0f);
    for (int d = 32; d > 0; d >>= 1) h += __shfl_down(h, d, 64);
    if (l == 0) hs[w] = h;
    __syncthreads();
    if (tid == 0) {
        float tot = hs[0] + hs[1] + hs[2] + hs[3];
        __hip_atomic_store(&blocksum[blockIdx.x], tot,
                           __ATOMIC_RELEASE, __HIP_MEMORY_SCOPE_AGENT);
        int prev = __hip_atomic_fetch_add(done, 1,
                                          __ATOMIC_ACQ_REL, __HIP_MEMORY_SCOPE_AGENT);
        lastflag = (prev == 31) ? 1 : 0;
    }
    __syncthreads();
    if (lastflag) {   // order-independent last-block final reduction
        float s2 = 0.0f;
        if (tid < 32)
            s2 = __hip_atomic_load(&blocksum[tid],
                                   __ATOMIC_ACQUIRE, __HIP_MEMORY_SCOPE_AGENT);
        if (tid < 64) {
            for (int d = 32; d > 0; d >>= 1) s2 += __shfl_down(s2, d, 64);
            if (tid == 0) out[0] = s2 * (1.0f / NROWS);
        }
    }
}

extern "C" void kernel_launch(void* const* d_in, const int* in_sizes, int n_in,
                              void* d_out, int out_size, void* d_ws, size_t ws_size,
                              hipStream_t stream) {
    const float* X = (const float*)d_in[0];
    const int* tgt = (const int*)d_in[1];
    float* out = (float*)d_out;

    float* f = (float*)d_ws;
    int*   hist     = (int*)f;                 // [0,256)
    float* S_class  = f + 256;                 // [256,512)
    int*   coffset  = (int*)(f + 512);         // [512,768)
    float* rowsum   = f + 768;                 // [768,896)
    int*   done     = (int*)(f + 896);         // 1 int
    float* bsum     = f + 1024;                // [1024,1280)
    float* blocksum = f + 1280;                // [1280,1312)
    int*   cstart   = (int*)(f + 1536);        // [1536,1793)
    float* sq       = f + 2048;                // [2048,10240)
    float* upk      = f + 10240;               // [10240,18432)
    unsigned int* Xbf  = (unsigned int*)(f + 18432);    // 2 MB: [18432,542720)
    unsigned int* Xbfn = (unsigned int*)(f + 542720);   // 2 MB: [542720,1067008)
    float4* partial = (float4*)(f + 1067008);  // ns*8192 float4

    int ns = 8;   // slice == XCD id
    while (ns > 2 && ws_size < ((size_t)1067008 + (size_t)ns * NROWS * 4) * sizeof(float))
        ns >>= 1;
    int shift = (ns == 8) ? 3 : (ns == 4) ? 2 : 1;
    int tiles = 64 / ns;

    histscan_kernel<<<1, 256, 0, stream>>>(tgt, hist, cstart, coffset,
                                           S_class, rowsum, done);
    prep_kernel<<<256, 256, 0, stream>>>(X, tgt, sq, upk, Xbf, Xbfn,
                                         coffset, S_class, bsum, rowsum);
    dist_kernel<<<128 * ns, 256, 0, stream>>>((const unsigned short*)Xbf,
                                              (const unsigned short*)Xbfn,
                                              upk, cstart, partial,
                                              ns - 1, shift, tiles);
    combine_kernel<<<32, 256, 0, stream>>>(sq, upk, Xbf, hist, S_class, bsum,
                                           rowsum, partial, blocksum, done, out, ns);
}

// Round 9
// 109.403 us; speedup vs baseline: 1.1315x; 1.1315x over previous
//
#include <hip/hip_runtime.h>
#include <math.h>

// TripletLoss round 14: 128-col strips (4 B-panels/block) -> 2x arithmetic
// intensity on A-traffic; spill-free at __launch_bounds__(256,2).
// (Round 13's (256,4) diet caused 20 MB of scratch spills: VGPR=64 < Bf alone.)
//
// Pipeline: histscan(1 blk) -> prep (class-sorted chunk-major scatter, pos+neg)
//           -> dist (MFMA Gram, acc seeded with u, negated A) -> combine.
//
// dist geometry: 512 blocks = 64 col-strips x 8 slices (slice==XCD, bx&7),
// 2 blocks/CU exactly. Per block: 128 cols (Bf[4][8] = 128 VGPR), 8 tiles of
// 128 rows. A-traffic halves vs 64-col: 128 MB ~ 3.7 us L2 < 6.9 us MFMA floor.
// acc (4x16 f32, AGPR side) seeded from upk -> MFMA computes v = u - x_i.x_j;
// fast tile (~97%) epilogue = min3 chains only; slow tiles keep 4 u live.

#define NROWS 8192
#define MARGIN_F 0.3f

typedef short bf16x8 __attribute__((ext_vector_type(8)));
typedef float f32x16 __attribute__((ext_vector_type(16)));
union U4B { uint4 u; bf16x8 h; };

__device__ __forceinline__ unsigned short f2bf(float x) {
    unsigned u = __float_as_uint(x);
    return (unsigned short)((u + 0x7fffu + ((u >> 16) & 1u)) >> 16);
}
__device__ __forceinline__ float bflo(unsigned u) { return __uint_as_float(u << 16); }
__device__ __forceinline__ float bfhi(unsigned u) { return __uint_as_float(u & 0xffff0000u); }

// ---- K0: hist + scan + zero-init (single block) ----
__global__ __launch_bounds__(256) void histscan_kernel(const int* __restrict__ tgt,
                                                       int* __restrict__ hist,
                                                       int* __restrict__ cstart,
                                                       int* __restrict__ coffset,
                                                       float* __restrict__ S_class,
                                                       float* __restrict__ rowsum,
                                                       int* __restrict__ done) {
    __shared__ int h[256];
    __shared__ int wsum[4];
    int t = threadIdx.x;
    h[t] = 0;
    S_class[t] = 0.0f;
    if (t < 128) rowsum[t] = 0.0f;
    if (t == 0) *done = 0;
    __syncthreads();
    const int4* t4 = (const int4*)tgt;
    for (int i = t; i < NROWS / 4; i += 256) {
        int4 v = t4[i];
        atomicAdd(&h[v.x], 1);
        atomicAdd(&h[v.y], 1);
        atomicAdd(&h[v.z], 1);
        atomicAdd(&h[v.w], 1);
    }
    __syncthreads();
    int hv = h[t];
    hist[t] = hv;
    int x = hv;
    #pragma unroll
    for (int d = 1; d < 64; d <<= 1) {
        int y = __shfl_up(x, d, 64);
        if ((t & 63) >= d) x += y;
    }
    if ((t & 63) == 63) wsum[t >> 6] = x;
    __syncthreads();
    int off = 0;
    for (int i = 0; i < (t >> 6); ++i) off += wsum[i];
    int excl = off + x - hv;        // exclusive prefix
    cstart[t] = excl;
    coffset[t] = excl;
    if (t == 255) cstart[256] = NROWS;
}

// ---- K1: bf16 convert + class-sorted chunk-major scatter (pos+neg) ----
__global__ __launch_bounds__(256) void prep_kernel(const float* __restrict__ X,
                                                   const int* __restrict__ tgt,
                                                   float* __restrict__ sq,
                                                   float* __restrict__ upk,
                                                   unsigned int* __restrict__ Xbf,
                                                   unsigned int* __restrict__ Xbfn,
                                                   int* __restrict__ coffset,
                                                   float* __restrict__ S_class,
                                                   float* __restrict__ bsum,
                                                   float* __restrict__ rowsum) {
    __shared__ float rsm[4][128];
    __shared__ float bs[4];
    int tid = threadIdx.x, w = tid >> 6, l = tid & 63;
    int bx = blockIdx.x;
    int row0 = bx * 32 + w * 8;

    unsigned h2s[8];
    float s8[8];
    int c8[8];
    float rsx = 0.0f, rsy = 0.0f, rs = 0.0f;

    #pragma unroll
    for (int i = 0; i < 8; ++i) {
        int r = row0 + i;
        float2 v = ((const float2*)X)[(size_t)r * 64 + l];
        unsigned hx = f2bf(v.x), hy = f2bf(v.y);
        h2s[i] = hx | (hy << 16);
        rsx += v.x; rsy += v.y;
        float s = v.x * v.x + v.y * v.y;
        for (int d = 32; d > 0; d >>= 1) s += __shfl_down(s, d, 64);
        if (l == 0) {
            c8[i] = tgt[r];
            s8[i] = s;
            rs += s;
        }
    }
    rsm[w][2 * l] = rsx;
    rsm[w][2 * l + 1] = rsy;
    if (l == 0) bs[w] = rs;
    __syncthreads();
    if (tid < 128)
        atomicAdd(&rowsum[tid], rsm[0][tid] + rsm[1][tid] + rsm[2][tid] + rsm[3][tid]);
    if (tid == 0) bsum[bx] = bs[0] + bs[1] + bs[2] + bs[3];

    #pragma unroll
    for (int i = 0; i < 8; ++i) {
        int pos = 0;
        if (l == 0) {
            int c = c8[i];
            pos = atomicAdd(&coffset[c], 1);   // absolute position
            sq[pos] = s8[i];
            upk[pos] = __uint_as_float((__float_as_uint(0.5f * s8[i]) & 0xffffff00u) | (unsigned)c);
            atomicAdd(&S_class[c], s8[i]);
        }
        pos = __shfl(pos, 0, 64);
        int g = pos >> 5, rr = pos & 31;
        size_t idx = ((size_t)(g * 16 + (l >> 2)) * 32 + rr) * 4 + (l & 3);
        unsigned hh = h2s[i];
        Xbf[idx] = hh;
        Xbfn[idx] = hh ^ 0x80008000u;
    }
}

// ---- K2: MFMA Gram, 128-col strips, negated-A + C-init fusion ----
__global__ __launch_bounds__(256, 2) void dist_kernel(
        const unsigned short* __restrict__ Xbf, const unsigned short* __restrict__ Xbfn,
        const float* __restrict__ upk, const int* __restrict__ cstart,
        float4* __restrict__ partial, int ns_mask, int jb_shift, int tiles) {
    __shared__ float4 sm[128 * 4];
    const int tid = threadIdx.x;
    const int w = tid >> 6, l = tid & 63, hl = l >> 5, l31 = l & 31;
    const int bx = blockIdx.x;
    const int slice = bx & ns_mask;   // == XCD id for ns=8
    const int jb = bx >> jb_shift;    // 128-col strip (64 strips)
    const int col0 = jb * 128;
    const uint4* Xq = (const uint4*)Xbf;
    const uint4* Xqn = (const uint4*)Xbfn;

    // B fragments: 4 panels of 32 cols (positive copy), 1 KB coalesced reads
    bf16x8 Bf[4][8];
    #pragma unroll
    for (int ct = 0; ct < 4; ++ct) {
        const uint4* bp = Xq + (size_t)(jb * 4 + ct) * 512 + hl * 32 + l31;
        #pragma unroll
        for (int kk = 0; kk < 8; ++kk) {
            U4B tb; tb.u = bp[kk * 64];
            Bf[ct][kk] = tb.h;
        }
    }
    int tjt[4];
    #pragma unroll
    for (int ct = 0; ct < 4; ++ct)
        tjt[ct] = __float_as_int(upk[col0 + ct * 32 + l31]) & 0xff;
    const int c_first = __float_as_int(upk[col0]) & 0xff;
    const int c_last  = __float_as_int(upk[col0 + 127]) & 0xff;
    const int U0 = cstart[c_first];
    const int U1 = cstart[c_last + 1];

    float Ss[4] = {0.f, 0.f, 0.f, 0.f};
    float Mp[4] = {-INFINITY, -INFINITY, -INFINITY, -INFINITY};
    float Mn[4] = { INFINITY,  INFINITY,  INFINITY,  INFINITY};
    const int row_base = slice * tiles * 128;

    for (int t = 0; t < tiles; ++t) {
        const int i0 = row_base + t * 128;
        const float4* up = (const float4*)(upk + i0 + w * 32 + 4 * hl);

        // seed acc[0] with u values, copy to the other 3 panels
        f32x16 acc[4];
        #pragma unroll
        for (int g = 0; g < 4; ++g) {
            float4 u4 = up[g * 2];
            acc[0][g * 4 + 0] = u4.x; acc[0][g * 4 + 1] = u4.y;
            acc[0][g * 4 + 2] = u4.z; acc[0][g * 4 + 3] = u4.w;
        }
        acc[1] = acc[0];
        acc[2] = acc[0];
        acc[3] = acc[0];

        // negated A: MFMA computes v = u - x_i.x_j ; 32 MFMAs per 8 A-loads
        const uint4* ap = Xqn + ((size_t)(i0 >> 5) + w) * 512 + hl * 32 + l31;
        #pragma unroll
        for (int kk = 0; kk < 8; ++kk) {
            U4B a; a.u = ap[kk * 64];
            acc[0] = __builtin_amdgcn_mfma_f32_32x32x16_bf16(a.h, Bf[0][kk], acc[0], 0, 0, 0);
            acc[1] = __builtin_amdgcn_mfma_f32_32x32x16_bf16(a.h, Bf[1][kk], acc[1], 0, 0, 0);
            acc[2] = __builtin_amdgcn_mfma_f32_32x32x16_bf16(a.h, Bf[2][kk], acc[2], 0, 0, 0);
            acc[3] = __builtin_amdgcn_mfma_f32_32x32x16_bf16(a.h, Bf[3][kk], acc[3], 0, 0, 0);
        }

        if (i0 < U1 && i0 + 128 > U0) {
            // slow tile (block-uniform, rare): keep only 4 u floats live
            #pragma unroll
            for (int g = 0; g < 4; ++g) {
                float4 u4 = up[g * 2];
                float uv[4] = {u4.x, u4.y, u4.z, u4.w};
                #pragma unroll
                for (int rr = 0; rr < 4; ++rr) {
                    const int r = g * 4 + rr;
                    const int utag = __float_as_int(uv[rr]) & 0xff;
                    #pragma unroll
                    for (int ct = 0; ct < 4; ++ct) {
                        float v = acc[ct][r];
                        bool same = (utag == tjt[ct]);
                        float a = uv[rr] - v;
                        Ss[ct] += same ? a : 0.0f;
                        Mp[ct] = fmaxf(Mp[ct], same ? v : -INFINITY);
                        Mn[ct] = same ? Mn[ct] : fminf(Mn[ct], v);
                    }
                }
            }
        } else {
            // fast tile: pure negatives -- min3 chains only
            #pragma unroll
            for (int ct = 0; ct < 4; ++ct) {
                #pragma unroll
                for (int r = 0; r < 16; r += 2)
                    Mn[ct] = fminf(fminf(acc[ct][r], acc[ct][r + 1]), Mn[ct]);
            }
        }
    }

    // merge half-lanes, then 4 waves via LDS, write coalesced partial
    #pragma unroll
    for (int ct = 0; ct < 4; ++ct) {
        Ss[ct] += __shfl_xor(Ss[ct], 32, 64);
        Mp[ct] = fmaxf(Mp[ct], __shfl_xor(Mp[ct], 32, 64));
        Mn[ct] = fminf(Mn[ct], __shfl_xor(Mn[ct], 32, 64));
    }
    if (l < 32) {
        #pragma unroll
        for (int ct = 0; ct < 4; ++ct)
            sm[(ct * 32 + l31) * 4 + w] = make_float4(Ss[ct], Mp[ct], Mn[ct], 0.0f);
    }
    __syncthreads();
    if (tid < 128) {
        float4 a = sm[tid * 4 + 0], b = sm[tid * 4 + 1];
        float4 c2 = sm[tid * 4 + 2], d = sm[tid * 4 + 3];
        float4 o;
        o.x = a.x + b.x + c2.x + d.x;
        o.y = fmaxf(fmaxf(a.y, b.y), fmaxf(c2.y, d.y));
        o.z = fminf(fminf(a.z, b.z), fminf(c2.z, d.z));
        o.w = 0.0f;
        partial[(size_t)slice * NROWS + col0 + tid] = o;
    }
}

// ---- K3: per-row loss (Sa via rowsum dot) + last-block final reduction ----
__global__ __launch_bounds__(256) void combine_kernel(
        const float* __restrict__ sq, const float* __restrict__ upk,
        const unsigned int* __restrict__ Xbf,
        const int* __restrict__ hist, const float* __restrict__ S_class,
        const float* __restrict__ bsum, const float* __restrict__ rowsum,
        const float4* __restrict__ partial,
        float* __restrict__ blocksum, int* __restrict__ done,
        float* __restrict__ out, int ns) {
    __shared__ float red[4];
    __shared__ float hs[4];
    __shared__ float rsl[128];
    __shared__ int lastflag;
    int tid = threadIdx.x, l = tid & 63, w = tid >> 6;

    if (tid < 128) rsl[tid] = rowsum[tid];

    // S_all = sum of prep's 256 per-block sums
    float b = bsum[tid];
    for (int d = 32; d > 0; d >>= 1) b += __shfl_down(b, d, 64);
    if (l == 0) red[w] = b;
    __syncthreads();
    float S_all = red[0] + red[1] + red[2] + red[3];

    int j = blockIdx.x * 256 + tid;
    float Ss = 0.f, Mp = -INFINITY, Mn = INFINITY;
    for (int s = 0; s < ns; ++s) {
        float4 p = partial[(size_t)s * NROWS + j];
        Ss += p.x;
        Mp = fmaxf(Mp, p.y); Mn = fminf(Mn, p.z);
    }

    // Sa_j = rowsum . x_j  (chunk-major bf16 row, coalesced across lanes)
    float sa = 0.0f;
    {
        const uint4* Xq = (const uint4*)Xbf;
        int g = j >> 5, rr = j & 31;
        #pragma unroll
        for (int c16 = 0; c16 < 16; ++c16) {
            uint4 q = Xq[((size_t)(g * 16 + c16)) * 32 + rr];
            int k0 = c16 * 8;
            sa = fmaf(bflo(q.x), rsl[k0 + 0], sa);
            sa = fmaf(bfhi(q.x), rsl[k0 + 1], sa);
            sa = fmaf(bflo(q.y), rsl[k0 + 2], sa);
            sa = fmaf(bfhi(q.y), rsl[k0 + 3], sa);
            sa = fmaf(bflo(q.z), rsl[k0 + 4], sa);
            sa = fmaf(bfhi(q.z), rsl[k0 + 5], sa);
            sa = fmaf(bflo(q.w), rsl[k0 + 6], sa);
            sa = fmaf(bfhi(q.w), rsl[k0 + 7], sa);
        }
    }

    float sqj = sq[j];
    int c = __float_as_int(upk[j]) & 0xff;
    float cnt = (float)hist[c];
    float sumall = (float)NROWS * sqj + S_all - 2.0f * sa;
    float sump = cnt * sqj + S_class[c] - 2.0f * Ss;
    float sumn = sumall - sump;
    float sigp = sump / (cnt - 1.0f);
    float sign_ = sumn / ((float)NROWS - cnt);
    float ap = (sqj + 2.0f * Mp) / sigp + 0.5f * __logf(sigp);
    float an = (sqj + 2.0f * Mn) / sign_ + 0.5f * __logf(sign_);
    float h = fmaxf(ap - an + MARGIN_F, 0.0f);
    for (int d = 32; d > 0; d >>= 1) h += __shfl_down(h, d, 64);
    if (l == 0) hs[w] = h;
    __syncthreads();
    if (tid == 0) {
        float tot = hs[0] + hs[1] + hs[2] + hs[3];
        __hip_atomic_store(&blocksum[blockIdx.x], tot,
                           __ATOMIC_RELEASE, __HIP_MEMORY_SCOPE_AGENT);
        int prev = __hip_atomic_fetch_add(done, 1,
                                          __ATOMIC_ACQ_REL, __HIP_MEMORY_SCOPE_AGENT);
        lastflag = (prev == 31) ? 1 : 0;
    }
    __syncthreads();
    if (lastflag) {   // order-independent last-block final reduction
        float s2 = 0.0f;
        if (tid < 32)
            s2 = __hip_atomic_load(&blocksum[tid],
                                   __ATOMIC_ACQUIRE, __HIP_MEMORY_SCOPE_AGENT);
        if (tid < 64) {
            for (int d = 32; d > 0; d >>= 1) s2 += __shfl_down(s2, d, 64);
            if (tid == 0) out[0] = s2 * (1.0f / NROWS);
        }
    }
}

extern "C" void kernel_launch(void* const* d_in, const int* in_sizes, int n_in,
                              void* d_out, int out_size, void* d_ws, size_t ws_size,
                              hipStream_t stream) {
    const float* X = (const float*)d_in[0];
    const int* tgt = (const int*)d_in[1];
    float* out = (float*)d_out;

    float* f = (float*)d_ws;
    int*   hist     = (int*)f;                 // [0,256)
    float* S_class  = f + 256;                 // [256,512)
    int*   coffset  = (int*)(f + 512);         // [512,768)
    float* rowsum   = f + 768;                 // [768,896)
    int*   done     = (int*)(f + 896);         // 1 int
    float* bsum     = f + 1024;                // [1024,1280)
    float* blocksum = f + 1280;                // [1280,1312)
    int*   cstart   = (int*)(f + 1536);        // [1536,1793)
    float* sq       = f + 2048;                // [2048,10240)
    float* upk      = f + 10240;               // [10240,18432)
    unsigned int* Xbf  = (unsigned int*)(f + 18432);    // 2 MB: [18432,542720)
    unsigned int* Xbfn = (unsigned int*)(f + 542720);   // 2 MB: [542720,1067008)
    float4* partial = (float4*)(f + 1067008);  // ns*8192 float4

    int ns = 8;   // slice == XCD id
    while (ns > 2 && ws_size < ((size_t)1067008 + (size_t)ns * NROWS * 4) * sizeof(float))
        ns >>= 1;
    int shift = (ns == 8) ? 3 : (ns == 4) ? 2 : 1;
    int tiles = 64 / ns;

    histscan_kernel<<<1, 256, 0, stream>>>(tgt, hist, cstart, coffset,
                                           S_class, rowsum, done);
    prep_kernel<<<256, 256, 0, stream>>>(X, tgt, sq, upk, Xbf, Xbfn,
                                         coffset, S_class, bsum, rowsum);
    dist_kernel<<<64 * ns, 256, 0, stream>>>((const unsigned short*)Xbf,
                                             (const unsigned short*)Xbfn,
                                             upk, cstart, partial,
                                             ns - 1, shift, tiles);
    combine_kernel<<<32, 256, 0, stream>>>(sq, upk, Xbf, hist, S_class, bsum,
                                           rowsum, partial, blocksum, done, out, ns);
}

// Round 11
// 106.538 us; speedup vs baseline: 1.1619x; 1.0269x over previous
//
#include <hip/hip_runtime.h>
#include <math.h>

// TripletLoss round 16 (= round 15 resubmitted; infra failure, no result).
// Round 14 minus the Xbfn array — B fragments are negated IN REGISTERS
// (once per block, 128 v_xor), so dist computes v = u + x_i.(-x_j) with a
// single positive Xbf (2 MB, XCD-L2-resident) and prep's scatter writes halve.
//
// Pipeline: histscan(1 blk) -> prep (class-sorted chunk-major scatter)
//           -> dist (MFMA Gram, acc seeded with u, negated-B) -> combine.
//
// dist geometry: 512 blocks = 64 col-strips x 8 slices (slice==XCD, bx&7),
// 2 blocks/CU exactly at __launch_bounds__(256,2) (no spills; R13 lesson:
// Bf[4][8] alone is 128 VGPR, never bound below ~256).
// Fast tile (~97%, class-sorted) epilogue = min3 chains only.

#define NROWS 8192
#define MARGIN_F 0.3f

typedef short bf16x8 __attribute__((ext_vector_type(8)));
typedef float f32x16 __attribute__((ext_vector_type(16)));
union U4B { uint4 u; bf16x8 h; };

__device__ __forceinline__ unsigned short f2bf(float x) {
    unsigned u = __float_as_uint(x);
    return (unsigned short)((u + 0x7fffu + ((u >> 16) & 1u)) >> 16);
}
__device__ __forceinline__ float bflo(unsigned u) { return __uint_as_float(u << 16); }
__device__ __forceinline__ float bfhi(unsigned u) { return __uint_as_float(u & 0xffff0000u); }

// ---- K0: hist + scan + zero-init (single block) ----
__global__ __launch_bounds__(256) void histscan_kernel(const int* __restrict__ tgt,
                                                       int* __restrict__ hist,
                                                       int* __restrict__ cstart,
                                                       int* __restrict__ coffset,
                                                       float* __restrict__ S_class,
                                                       float* __restrict__ rowsum,
                                                       int* __restrict__ done) {
    __shared__ int h[256];
    __shared__ int wsum[4];
    int t = threadIdx.x;
    h[t] = 0;
    S_class[t] = 0.0f;
    if (t < 128) rowsum[t] = 0.0f;
    if (t == 0) *done = 0;
    __syncthreads();
    const int4* t4 = (const int4*)tgt;
    for (int i = t; i < NROWS / 4; i += 256) {
        int4 v = t4[i];
        atomicAdd(&h[v.x], 1);
        atomicAdd(&h[v.y], 1);
        atomicAdd(&h[v.z], 1);
        atomicAdd(&h[v.w], 1);
    }
    __syncthreads();
    int hv = h[t];
    hist[t] = hv;
    int x = hv;
    #pragma unroll
    for (int d = 1; d < 64; d <<= 1) {
        int y = __shfl_up(x, d, 64);
        if ((t & 63) >= d) x += y;
    }
    if ((t & 63) == 63) wsum[t >> 6] = x;
    __syncthreads();
    int off = 0;
    for (int i = 0; i < (t >> 6); ++i) off += wsum[i];
    int excl = off + x - hv;        // exclusive prefix
    cstart[t] = excl;
    coffset[t] = excl;
    if (t == 255) cstart[256] = NROWS;
}

// ---- K1: bf16 convert + class-sorted chunk-major scatter ----
__global__ __launch_bounds__(256) void prep_kernel(const float* __restrict__ X,
                                                   const int* __restrict__ tgt,
                                                   float* __restrict__ sq,
                                                   float* __restrict__ upk,
                                                   unsigned int* __restrict__ Xbf,
                                                   int* __restrict__ coffset,
                                                   float* __restrict__ S_class,
                                                   float* __restrict__ bsum,
                                                   float* __restrict__ rowsum) {
    __shared__ float rsm[4][128];
    __shared__ float bs[4];
    int tid = threadIdx.x, w = tid >> 6, l = tid & 63;
    int bx = blockIdx.x;
    int row0 = bx * 32 + w * 8;

    unsigned h2s[8];
    float s8[8];
    int c8[8];
    float rsx = 0.0f, rsy = 0.0f, rs = 0.0f;

    #pragma unroll
    for (int i = 0; i < 8; ++i) {
        int r = row0 + i;
        float2 v = ((const float2*)X)[(size_t)r * 64 + l];
        unsigned hx = f2bf(v.x), hy = f2bf(v.y);
        h2s[i] = hx | (hy << 16);
        rsx += v.x; rsy += v.y;
        float s = v.x * v.x + v.y * v.y;
        for (int d = 32; d > 0; d >>= 1) s += __shfl_down(s, d, 64);
        if (l == 0) {
            c8[i] = tgt[r];
            s8[i] = s;
            rs += s;
        }
    }
    rsm[w][2 * l] = rsx;
    rsm[w][2 * l + 1] = rsy;
    if (l == 0) bs[w] = rs;
    __syncthreads();
    if (tid < 128)
        atomicAdd(&rowsum[tid], rsm[0][tid] + rsm[1][tid] + rsm[2][tid] + rsm[3][tid]);
    if (tid == 0) bsum[bx] = bs[0] + bs[1] + bs[2] + bs[3];

    #pragma unroll
    for (int i = 0; i < 8; ++i) {
        int pos = 0;
        if (l == 0) {
            int c = c8[i];
            pos = atomicAdd(&coffset[c], 1);   // absolute position
            sq[pos] = s8[i];
            upk[pos] = __uint_as_float((__float_as_uint(0.5f * s8[i]) & 0xffffff00u) | (unsigned)c);
            atomicAdd(&S_class[c], s8[i]);
        }
        pos = __shfl(pos, 0, 64);
        int g = pos >> 5, rr = pos & 31;
        size_t idx = ((size_t)(g * 16 + (l >> 2)) * 32 + rr) * 4 + (l & 3);
        Xbf[idx] = h2s[i];
    }
}

// ---- K2: MFMA Gram, 128-col strips, negated-B + C-init fusion ----
__global__ __launch_bounds__(256, 2) void dist_kernel(
        const unsigned short* __restrict__ Xbf,
        const float* __restrict__ upk, const int* __restrict__ cstart,
        float4* __restrict__ partial, int ns_mask, int jb_shift, int tiles) {
    __shared__ float4 sm[128 * 4];
    const int tid = threadIdx.x;
    const int w = tid >> 6, l = tid & 63, hl = l >> 5, l31 = l & 31;
    const int bx = blockIdx.x;
    const int slice = bx & ns_mask;   // == XCD id for ns=8
    const int jb = bx >> jb_shift;    // 128-col strip (64 strips)
    const int col0 = jb * 128;
    const uint4* Xq = (const uint4*)Xbf;

    // B fragments: 4 panels of 32 cols, negated in registers (sign-bit XOR)
    bf16x8 Bf[4][8];
    #pragma unroll
    for (int ct = 0; ct < 4; ++ct) {
        const uint4* bp = Xq + (size_t)(jb * 4 + ct) * 512 + hl * 32 + l31;
        #pragma unroll
        for (int kk = 0; kk < 8; ++kk) {
            U4B tb; tb.u = bp[kk * 64];
            tb.u.x ^= 0x80008000u;
            tb.u.y ^= 0x80008000u;
            tb.u.z ^= 0x80008000u;
            tb.u.w ^= 0x80008000u;
            Bf[ct][kk] = tb.h;
        }
    }
    int tjt[4];
    #pragma unroll
    for (int ct = 0; ct < 4; ++ct)
        tjt[ct] = __float_as_int(upk[col0 + ct * 32 + l31]) & 0xff;
    const int c_first = __float_as_int(upk[col0]) & 0xff;
    const int c_last  = __float_as_int(upk[col0 + 127]) & 0xff;
    const int U0 = cstart[c_first];
    const int U1 = cstart[c_last + 1];

    float Ss[4] = {0.f, 0.f, 0.f, 0.f};
    float Mp[4] = {-INFINITY, -INFINITY, -INFINITY, -INFINITY};
    float Mn[4] = { INFINITY,  INFINITY,  INFINITY,  INFINITY};
    const int row_base = slice * tiles * 128;

    for (int t = 0; t < tiles; ++t) {
        const int i0 = row_base + t * 128;
        const float4* up = (const float4*)(upk + i0 + w * 32 + 4 * hl);

        // seed acc[0] with u values, copy to the other 3 panels
        f32x16 acc[4];
        #pragma unroll
        for (int g = 0; g < 4; ++g) {
            float4 u4 = up[g * 2];
            acc[0][g * 4 + 0] = u4.x; acc[0][g * 4 + 1] = u4.y;
            acc[0][g * 4 + 2] = u4.z; acc[0][g * 4 + 3] = u4.w;
        }
        acc[1] = acc[0];
        acc[2] = acc[0];
        acc[3] = acc[0];

        // negated B: MFMA computes v = u - x_i.x_j ; 32 MFMAs per 8 A-loads
        const uint4* ap = Xq + ((size_t)(i0 >> 5) + w) * 512 + hl * 32 + l31;
        #pragma unroll
        for (int kk = 0; kk < 8; ++kk) {
            U4B a; a.u = ap[kk * 64];
            acc[0] = __builtin_amdgcn_mfma_f32_32x32x16_bf16(a.h, Bf[0][kk], acc[0], 0, 0, 0);
            acc[1] = __builtin_amdgcn_mfma_f32_32x32x16_bf16(a.h, Bf[1][kk], acc[1], 0, 0, 0);
            acc[2] = __builtin_amdgcn_mfma_f32_32x32x16_bf16(a.h, Bf[2][kk], acc[2], 0, 0, 0);
            acc[3] = __builtin_amdgcn_mfma_f32_32x32x16_bf16(a.h, Bf[3][kk], acc[3], 0, 0, 0);
        }

        if (i0 < U1 && i0 + 128 > U0) {
            // slow tile (block-uniform, rare): keep only 4 u floats live
            #pragma unroll
            for (int g = 0; g < 4; ++g) {
                float4 u4 = up[g * 2];
                float uv[4] = {u4.x, u4.y, u4.z, u4.w};
                #pragma unroll
                for (int rr = 0; rr < 4; ++rr) {
                    const int r = g * 4 + rr;
                    const int utag = __float_as_int(uv[rr]) & 0xff;
                    #pragma unroll
                    for (int ct = 0; ct < 4; ++ct) {
                        float v = acc[ct][r];
                        bool same = (utag == tjt[ct]);
                        float a = uv[rr] - v;
                        Ss[ct] += same ? a : 0.0f;
                        Mp[ct] = fmaxf(Mp[ct], same ? v : -INFINITY);
                        Mn[ct] = same ? Mn[ct] : fminf(Mn[ct], v);
                    }
                }
            }
        } else {
            // fast tile: pure negatives -- min3 chains only
            #pragma unroll
            for (int ct = 0; ct < 4; ++ct) {
                #pragma unroll
                for (int r = 0; r < 16; r += 2)
                    Mn[ct] = fminf(fminf(acc[ct][r], acc[ct][r + 1]), Mn[ct]);
            }
        }
    }

    // merge half-lanes, then 4 waves via LDS, write coalesced partial
    #pragma unroll
    for (int ct = 0; ct < 4; ++ct) {
        Ss[ct] += __shfl_xor(Ss[ct], 32, 64);
        Mp[ct] = fmaxf(Mp[ct], __shfl_xor(Mp[ct], 32, 64));
        Mn[ct] = fminf(Mn[ct], __shfl_xor(Mn[ct], 32, 64));
    }
    if (l < 32) {
        #pragma unroll
        for (int ct = 0; ct < 4; ++ct)
            sm[(ct * 32 + l31) * 4 + w] = make_float4(Ss[ct], Mp[ct], Mn[ct], 0.0f);
    }
    __syncthreads();
    if (tid < 128) {
        float4 a = sm[tid * 4 + 0], b = sm[tid * 4 + 1];
        float4 c2 = sm[tid * 4 + 2], d = sm[tid * 4 + 3];
        float4 o;
        o.x = a.x + b.x + c2.x + d.x;
        o.y = fmaxf(fmaxf(a.y, b.y), fmaxf(c2.y, d.y));
        o.z = fminf(fminf(a.z, b.z), fminf(c2.z, d.z));
        o.w = 0.0f;
        partial[(size_t)slice * NROWS + col0 + tid] = o;
    }
}

// ---- K3: per-row loss (Sa via rowsum dot) + last-block final reduction ----
__global__ __launch_bounds__(256) void combine_kernel(
        const float* __restrict__ sq, const float* __restrict__ upk,
        const unsigned int* __restrict__ Xbf,
        const int* __restrict__ hist, const float* __restrict__ S_class,
        const float* __restrict__ bsum, const float* __restrict__ rowsum,
        const float4* __restrict__ partial,
        float* __restrict__ blocksum, int* __restrict__ done,
        float* __restrict__ out, int ns) {
    __shared__ float red[4];
    __shared__ float hs[4];
    __shared__ float rsl[128];
    __shared__ int lastflag;
    int tid = threadIdx.x, l = tid & 63, w = tid >> 6;

    if (tid < 128) rsl[tid] = rowsum[tid];

    // S_all = sum of prep's 256 per-block sums
    float b = bsum[tid];
    for (int d = 32; d > 0; d >>= 1) b += __shfl_down(b, d, 64);
    if (l == 0) red[w] = b;
    __syncthreads();
    float S_all = red[0] + red[1] + red[2] + red[3];

    int j = blockIdx.x * 256 + tid;
    float Ss = 0.f, Mp = -INFINITY, Mn = INFINITY;
    for (int s = 0; s < ns; ++s) {
        float4 p = partial[(size_t)s * NROWS + j];
        Ss += p.x;
        Mp = fmaxf(Mp, p.y); Mn = fminf(Mn, p.z);
    }

    // Sa_j = rowsum . x_j  (chunk-major bf16 row, coalesced across lanes)
    float sa = 0.0f;
    {
        const uint4* Xq = (const uint4*)Xbf;
        int g = j >> 5, rr = j & 31;
        #pragma unroll
        for (int c16 = 0; c16 < 16; ++c16) {
            uint4 q = Xq[((size_t)(g * 16 + c16)) * 32 + rr];
            int k0 = c16 * 8;
            sa = fmaf(bflo(q.x), rsl[k0 + 0], sa);
            sa = fmaf(bfhi(q.x), rsl[k0 + 1], sa);
            sa = fmaf(bflo(q.y), rsl[k0 + 2], sa);
            sa = fmaf(bfhi(q.y), rsl[k0 + 3], sa);
            sa = fmaf(bflo(q.z), rsl[k0 + 4], sa);
            sa = fmaf(bfhi(q.z), rsl[k0 + 5], sa);
            sa = fmaf(bflo(q.w), rsl[k0 + 6], sa);
            sa = fmaf(bfhi(q.w), rsl[k0 + 7], sa);
        }
    }

    float sqj = sq[j];
    int c = __float_as_int(upk[j]) & 0xff;
    float cnt = (float)hist[c];
    float sumall = (float)NROWS * sqj + S_all - 2.0f * sa;
    float sump = cnt * sqj + S_class[c] - 2.0f * Ss;
    float sumn = sumall - sump;
    float sigp = sump / (cnt - 1.0f);
    float sign_ = sumn / ((float)NROWS - cnt);
    float ap = (sqj + 2.0f * Mp) / sigp + 0.5f * __logf(sigp);
    float an = (sqj + 2.0f * Mn) / sign_ + 0.5f * __logf(sign_);
    float h = fmaxf(ap - an + MARGIN_F, 0.0f);
    for (int d = 32; d > 0; d >>= 1) h += __shfl_down(h, d, 64);
    if (l == 0) hs[w] = h;
    __syncthreads();
    if (tid == 0) {
        float tot = hs[0] + hs[1] + hs[2] + hs[3];
        __hip_atomic_store(&blocksum[blockIdx.x], tot,
                           __ATOMIC_RELEASE, __HIP_MEMORY_SCOPE_AGENT);
        int prev = __hip_atomic_fetch_add(done, 1,
                                          __ATOMIC_ACQ_REL, __HIP_MEMORY_SCOPE_AGENT);
        lastflag = (prev == 31) ? 1 : 0;
    }
    __syncthreads();
    if (lastflag) {   // order-independent last-block final reduction
        float s2 = 0.0f;
        if (tid < 32)
            s2 = __hip_atomic_load(&blocksum[tid],
                                   __ATOMIC_ACQUIRE, __HIP_MEMORY_SCOPE_AGENT);
        if (tid < 64) {
            for (int d = 32; d > 0; d >>= 1) s2 += __shfl_down(s2, d, 64);
            if (tid == 0) out[0] = s2 * (1.0f / NROWS);
        }
    }
}

extern "C" void kernel_launch(void* const* d_in, const int* in_sizes, int n_in,
                              void* d_out, int out_size, void* d_ws, size_t ws_size,
                              hipStream_t stream) {
    const float* X = (const float*)d_in[0];
    const int* tgt = (const int*)d_in[1];
    float* out = (float*)d_out;

    float* f = (float*)d_ws;
    int*   hist     = (int*)f;                 // [0,256)
    float* S_class  = f + 256;                 // [256,512)
    int*   coffset  = (int*)(f + 512);         // [512,768)
    float* rowsum   = f + 768;                 // [768,896)
    int*   done     = (int*)(f + 896);         // 1 int
    float* bsum     = f + 1024;                // [1024,1280)
    float* blocksum = f + 1280;                // [1280,1312)
    int*   cstart   = (int*)(f + 1536);        // [1536,1793)
    float* sq       = f + 2048;                // [2048,10240)
    float* upk      = f + 10240;               // [10240,18432)
    unsigned int* Xbf = (unsigned int*)(f + 18432);   // 2 MB: [18432,542720)
    float4* partial = (float4*)(f + 542720);   // ns*8192 float4

    int ns = 8;   // slice == XCD id
    while (ns > 2 && ws_size < ((size_t)542720 + (size_t)ns * NROWS * 4) * sizeof(float))
        ns >>= 1;
    int shift = (ns == 8) ? 3 : (ns == 4) ? 2 : 1;
    int tiles = 64 / ns;

    histscan_kernel<<<1, 256, 0, stream>>>(tgt, hist, cstart, coffset,
                                           S_class, rowsum, done);
    prep_kernel<<<256, 256, 0, stream>>>(X, tgt, sq, upk, Xbf,
                                         coffset, S_class, bsum, rowsum);
    dist_kernel<<<64 * ns, 256, 0, stream>>>((const unsigned short*)Xbf,
                                             upk, cstart, partial,
                                             ns - 1, shift, tiles);
    combine_kernel<<<32, 256, 0, stream>>>(sq, upk, Xbf, hist, S_class, bsum,
                                           rowsum, partial, blocksum, done, out, ns);
}

// Round 12
// 105.342 us; speedup vs baseline: 1.1751x; 1.0114x over previous
//
#include <hip/hip_runtime.h>
#include <math.h>

// TripletLoss round 17: round 16 + occupancy fixes on the latency-bound
// fixed-cost kernels: prep 512 blocks x 16 rows (2 blocks/CU), histscan
// 1024 threads (16 waves). dist/combine algebra untouched.
//
// Pipeline: histscan(1 blk, 1024 thr) -> prep (class-sorted chunk-major
// scatter, 512 blocks) -> dist (MFMA Gram, acc seeded with u, negated-B)
// -> combine (per-row loss, Sa = rowsum.x_j, last-block final).
//
// dist geometry: 512 blocks = 64 col-strips x 8 slices (slice==XCD, bx&7),
// 2 blocks/CU at __launch_bounds__(256,2), Bf[4][8]+acc[4] ~ 200 VGPR, no
// spills. Fast tile (~97%, class-sorted) epilogue = min3 chains only.

#define NROWS 8192
#define MARGIN_F 0.3f

typedef short bf16x8 __attribute__((ext_vector_type(8)));
typedef float f32x16 __attribute__((ext_vector_type(16)));
union U4B { uint4 u; bf16x8 h; };

__device__ __forceinline__ unsigned short f2bf(float x) {
    unsigned u = __float_as_uint(x);
    return (unsigned short)((u + 0x7fffu + ((u >> 16) & 1u)) >> 16);
}
__device__ __forceinline__ float bflo(unsigned u) { return __uint_as_float(u << 16); }
__device__ __forceinline__ float bfhi(unsigned u) { return __uint_as_float(u & 0xffff0000u); }

// ---- K0: hist + scan + zero-init (single block, 1024 threads) ----
__global__ __launch_bounds__(1024) void histscan_kernel(const int* __restrict__ tgt,
                                                        int* __restrict__ hist,
                                                        int* __restrict__ cstart,
                                                        int* __restrict__ coffset,
                                                        float* __restrict__ S_class,
                                                        float* __restrict__ rowsum,
                                                        int* __restrict__ done) {
    __shared__ int h[256];
    __shared__ int wsum[16];
    int t = threadIdx.x;
    if (t < 256) { h[t] = 0; S_class[t] = 0.0f; }
    if (t < 128) rowsum[t] = 0.0f;
    if (t == 0) *done = 0;
    __syncthreads();
    const int4* t4 = (const int4*)tgt;
    #pragma unroll
    for (int i = t; i < NROWS / 4; i += 1024) {
        int4 v = t4[i];
        atomicAdd(&h[v.x], 1);
        atomicAdd(&h[v.y], 1);
        atomicAdd(&h[v.z], 1);
        atomicAdd(&h[v.w], 1);
    }
    __syncthreads();
    int hv = (t < 256) ? h[t] : 0;
    int x = hv;
    #pragma unroll
    for (int d = 1; d < 64; d <<= 1) {
        int y = __shfl_up(x, d, 64);
        if ((t & 63) >= d) x += y;
    }
    if ((t & 63) == 63) wsum[t >> 6] = x;
    __syncthreads();
    if (t < 256) {
        int off = 0;
        for (int i = 0; i < (t >> 6); ++i) off += wsum[i];
        int excl = off + x - hv;    // exclusive prefix
        hist[t] = hv;
        cstart[t] = excl;
        coffset[t] = excl;
        if (t == 255) cstart[256] = NROWS;
    }
}

// ---- K1: bf16 convert + class-sorted chunk-major scatter (512 blocks) ----
__global__ __launch_bounds__(256) void prep_kernel(const float* __restrict__ X,
                                                   const int* __restrict__ tgt,
                                                   float* __restrict__ sq,
                                                   float* __restrict__ upk,
                                                   unsigned int* __restrict__ Xbf,
                                                   int* __restrict__ coffset,
                                                   float* __restrict__ S_class,
                                                   float* __restrict__ bsum,
                                                   float* __restrict__ rowsum) {
    __shared__ float rsm[4][128];
    __shared__ float bs[4];
    int tid = threadIdx.x, w = tid >> 6, l = tid & 63;
    int bx = blockIdx.x;
    int row0 = bx * 16 + w * 4;

    unsigned h2s[4];
    float s8[4];
    int c8[4];
    float rsx = 0.0f, rsy = 0.0f, rs = 0.0f;

    #pragma unroll
    for (int i = 0; i < 4; ++i) {
        int r = row0 + i;
        float2 v = ((const float2*)X)[(size_t)r * 64 + l];
        unsigned hx = f2bf(v.x), hy = f2bf(v.y);
        h2s[i] = hx | (hy << 16);
        rsx += v.x; rsy += v.y;
        float s = v.x * v.x + v.y * v.y;
        for (int d = 32; d > 0; d >>= 1) s += __shfl_down(s, d, 64);
        if (l == 0) {
            c8[i] = tgt[r];
            s8[i] = s;
            rs += s;
        }
    }
    rsm[w][2 * l] = rsx;
    rsm[w][2 * l + 1] = rsy;
    if (l == 0) bs[w] = rs;
    __syncthreads();
    if (tid < 128)
        atomicAdd(&rowsum[tid], rsm[0][tid] + rsm[1][tid] + rsm[2][tid] + rsm[3][tid]);
    if (tid == 0) bsum[bx] = bs[0] + bs[1] + bs[2] + bs[3];

    #pragma unroll
    for (int i = 0; i < 4; ++i) {
        int pos = 0;
        if (l == 0) {
            int c = c8[i];
            pos = atomicAdd(&coffset[c], 1);   // absolute position
            sq[pos] = s8[i];
            upk[pos] = __uint_as_float((__float_as_uint(0.5f * s8[i]) & 0xffffff00u) | (unsigned)c);
            atomicAdd(&S_class[c], s8[i]);
        }
        pos = __shfl(pos, 0, 64);
        int g = pos >> 5, rr = pos & 31;
        size_t idx = ((size_t)(g * 16 + (l >> 2)) * 32 + rr) * 4 + (l & 3);
        Xbf[idx] = h2s[i];
    }
}

// ---- K2: MFMA Gram, 128-col strips, negated-B + C-init fusion ----
__global__ __launch_bounds__(256, 2) void dist_kernel(
        const unsigned short* __restrict__ Xbf,
        const float* __restrict__ upk, const int* __restrict__ cstart,
        float4* __restrict__ partial, int ns_mask, int jb_shift, int tiles) {
    __shared__ float4 sm[128 * 4];
    const int tid = threadIdx.x;
    const int w = tid >> 6, l = tid & 63, hl = l >> 5, l31 = l & 31;
    const int bx = blockIdx.x;
    const int slice = bx & ns_mask;   // == XCD id for ns=8
    const int jb = bx >> jb_shift;    // 128-col strip (64 strips)
    const int col0 = jb * 128;
    const uint4* Xq = (const uint4*)Xbf;

    // B fragments: 4 panels of 32 cols, negated in registers (sign-bit XOR)
    bf16x8 Bf[4][8];
    #pragma unroll
    for (int ct = 0; ct < 4; ++ct) {
        const uint4* bp = Xq + (size_t)(jb * 4 + ct) * 512 + hl * 32 + l31;
        #pragma unroll
        for (int kk = 0; kk < 8; ++kk) {
            U4B tb; tb.u = bp[kk * 64];
            tb.u.x ^= 0x80008000u;
            tb.u.y ^= 0x80008000u;
            tb.u.z ^= 0x80008000u;
            tb.u.w ^= 0x80008000u;
            Bf[ct][kk] = tb.h;
        }
    }
    int tjt[4];
    #pragma unroll
    for (int ct = 0; ct < 4; ++ct)
        tjt[ct] = __float_as_int(upk[col0 + ct * 32 + l31]) & 0xff;
    const int c_first = __float_as_int(upk[col0]) & 0xff;
    const int c_last  = __float_as_int(upk[col0 + 127]) & 0xff;
    const int U0 = cstart[c_first];
    const int U1 = cstart[c_last + 1];

    float Ss[4] = {0.f, 0.f, 0.f, 0.f};
    float Mp[4] = {-INFINITY, -INFINITY, -INFINITY, -INFINITY};
    float Mn[4] = { INFINITY,  INFINITY,  INFINITY,  INFINITY};
    const int row_base = slice * tiles * 128;

    for (int t = 0; t < tiles; ++t) {
        const int i0 = row_base + t * 128;
        const float4* up = (const float4*)(upk + i0 + w * 32 + 4 * hl);

        // seed acc[0] with u values, copy to the other 3 panels
        f32x16 acc[4];
        #pragma unroll
        for (int g = 0; g < 4; ++g) {
            float4 u4 = up[g * 2];
            acc[0][g * 4 + 0] = u4.x; acc[0][g * 4 + 1] = u4.y;
            acc[0][g * 4 + 2] = u4.z; acc[0][g * 4 + 3] = u4.w;
        }
        acc[1] = acc[0];
        acc[2] = acc[0];
        acc[3] = acc[0];

        // negated B: MFMA computes v = u - x_i.x_j ; 32 MFMAs per 8 A-loads
        const uint4* ap = Xq + ((size_t)(i0 >> 5) + w) * 512 + hl * 32 + l31;
        #pragma unroll
        for (int kk = 0; kk < 8; ++kk) {
            U4B a; a.u = ap[kk * 64];
            acc[0] = __builtin_amdgcn_mfma_f32_32x32x16_bf16(a.h, Bf[0][kk], acc[0], 0, 0, 0);
            acc[1] = __builtin_amdgcn_mfma_f32_32x32x16_bf16(a.h, Bf[1][kk], acc[1], 0, 0, 0);
            acc[2] = __builtin_amdgcn_mfma_f32_32x32x16_bf16(a.h, Bf[2][kk], acc[2], 0, 0, 0);
            acc[3] = __builtin_amdgcn_mfma_f32_32x32x16_bf16(a.h, Bf[3][kk], acc[3], 0, 0, 0);
        }

        if (i0 < U1 && i0 + 128 > U0) {
            // slow tile (block-uniform, rare): keep only 4 u floats live
            #pragma unroll
            for (int g = 0; g < 4; ++g) {
                float4 u4 = up[g * 2];
                float uv[4] = {u4.x, u4.y, u4.z, u4.w};
                #pragma unroll
                for (int rr = 0; rr < 4; ++rr) {
                    const int r = g * 4 + rr;
                    const int utag = __float_as_int(uv[rr]) & 0xff;
                    #pragma unroll
                    for (int ct = 0; ct < 4; ++ct) {
                        float v = acc[ct][r];
                        bool same = (utag == tjt[ct]);
                        float a = uv[rr] - v;
                        Ss[ct] += same ? a : 0.0f;
                        Mp[ct] = fmaxf(Mp[ct], same ? v : -INFINITY);
                        Mn[ct] = same ? Mn[ct] : fminf(Mn[ct], v);
                    }
                }
            }
        } else {
            // fast tile: pure negatives -- min3 chains only
            #pragma unroll
            for (int ct = 0; ct < 4; ++ct) {
                #pragma unroll
                for (int r = 0; r < 16; r += 2)
                    Mn[ct] = fminf(fminf(acc[ct][r], acc[ct][r + 1]), Mn[ct]);
            }
        }
    }

    // merge half-lanes, then 4 waves via LDS, write coalesced partial
    #pragma unroll
    for (int ct = 0; ct < 4; ++ct) {
        Ss[ct] += __shfl_xor(Ss[ct], 32, 64);
        Mp[ct] = fmaxf(Mp[ct], __shfl_xor(Mp[ct], 32, 64));
        Mn[ct] = fminf(Mn[ct], __shfl_xor(Mn[ct], 32, 64));
    }
    if (l < 32) {
        #pragma unroll
        for (int ct = 0; ct < 4; ++ct)
            sm[(ct * 32 + l31) * 4 + w] = make_float4(Ss[ct], Mp[ct], Mn[ct], 0.0f);
    }
    __syncthreads();
    if (tid < 128) {
        float4 a = sm[tid * 4 + 0], b = sm[tid * 4 + 1];
        float4 c2 = sm[tid * 4 + 2], d = sm[tid * 4 + 3];
        float4 o;
        o.x = a.x + b.x + c2.x + d.x;
        o.y = fmaxf(fmaxf(a.y, b.y), fmaxf(c2.y, d.y));
        o.z = fminf(fminf(a.z, b.z), fminf(c2.z, d.z));
        o.w = 0.0f;
        partial[(size_t)slice * NROWS + col0 + tid] = o;
    }
}

// ---- K3: per-row loss (Sa via rowsum dot) + last-block final reduction ----
__global__ __launch_bounds__(256) void combine_kernel(
        const float* __restrict__ sq, const float* __restrict__ upk,
        const unsigned int* __restrict__ Xbf,
        const int* __restrict__ hist, const float* __restrict__ S_class,
        const float* __restrict__ bsum, const float* __restrict__ rowsum,
        const float4* __restrict__ partial,
        float* __restrict__ blocksum, int* __restrict__ done,
        float* __restrict__ out, int ns) {
    __shared__ float red[4];
    __shared__ float hs[4];
    __shared__ float rsl[128];
    __shared__ int lastflag;
    int tid = threadIdx.x, l = tid & 63, w = tid >> 6;

    if (tid < 128) rsl[tid] = rowsum[tid];

    // S_all = sum of prep's 512 per-block sums
    float b = bsum[tid] + bsum[tid + 256];
    for (int d = 32; d > 0; d >>= 1) b += __shfl_down(b, d, 64);
    if (l == 0) red[w] = b;
    __syncthreads();
    float S_all = red[0] + red[1] + red[2] + red[3];

    int j = blockIdx.x * 256 + tid;
    float Ss = 0.f, Mp = -INFINITY, Mn = INFINITY;
    for (int s = 0; s < ns; ++s) {
        float4 p = partial[(size_t)s * NROWS + j];
        Ss += p.x;
        Mp = fmaxf(Mp, p.y); Mn = fminf(Mn, p.z);
    }

    // Sa_j = rowsum . x_j  (chunk-major bf16 row, coalesced across lanes)
    float sa = 0.0f;
    {
        const uint4* Xq = (const uint4*)Xbf;
        int g = j >> 5, rr = j & 31;
        #pragma unroll
        for (int c16 = 0; c16 < 16; ++c16) {
            uint4 q = Xq[((size_t)(g * 16 + c16)) * 32 + rr];
            int k0 = c16 * 8;
            sa = fmaf(bflo(q.x), rsl[k0 + 0], sa);
            sa = fmaf(bfhi(q.x), rsl[k0 + 1], sa);
            sa = fmaf(bflo(q.y), rsl[k0 + 2], sa);
            sa = fmaf(bfhi(q.y), rsl[k0 + 3], sa);
            sa = fmaf(bflo(q.z), rsl[k0 + 4], sa);
            sa = fmaf(bfhi(q.z), rsl[k0 + 5], sa);
            sa = fmaf(bflo(q.w), rsl[k0 + 6], sa);
            sa = fmaf(bfhi(q.w), rsl[k0 + 7], sa);
        }
    }

    float sqj = sq[j];
    int c = __float_as_int(upk[j]) & 0xff;
    float cnt = (float)hist[c];
    float sumall = (float)NROWS * sqj + S_all - 2.0f * sa;
    float sump = cnt * sqj + S_class[c] - 2.0f * Ss;
    float sumn = sumall - sump;
    float sigp = sump / (cnt - 1.0f);
    float sign_ = sumn / ((float)NROWS - cnt);
    float ap = (sqj + 2.0f * Mp) / sigp + 0.5f * __logf(sigp);
    float an = (sqj + 2.0f * Mn) / sign_ + 0.5f * __logf(sign_);
    float h = fmaxf(ap - an + MARGIN_F, 0.0f);
    for (int d = 32; d > 0; d >>= 1) h += __shfl_down(h, d, 64);
    if (l == 0) hs[w] = h;
    __syncthreads();
    if (tid == 0) {
        float tot = hs[0] + hs[1] + hs[2] + hs[3];
        __hip_atomic_store(&blocksum[blockIdx.x], tot,
                           __ATOMIC_RELEASE, __HIP_MEMORY_SCOPE_AGENT);
        int prev = __hip_atomic_fetch_add(done, 1,
                                          __ATOMIC_ACQ_REL, __HIP_MEMORY_SCOPE_AGENT);
        lastflag = (prev == 31) ? 1 : 0;
    }
    __syncthreads();
    if (lastflag) {   // order-independent last-block final reduction
        float s2 = 0.0f;
        if (tid < 32)
            s2 = __hip_atomic_load(&blocksum[tid],
                                   __ATOMIC_ACQUIRE, __HIP_MEMORY_SCOPE_AGENT);
        if (tid < 64) {
            for (int d = 32; d > 0; d >>= 1) s2 += __shfl_down(s2, d, 64);
            if (tid == 0) out[0] = s2 * (1.0f / NROWS);
        }
    }
}

extern "C" void kernel_launch(void* const* d_in, const int* in_sizes, int n_in,
                              void* d_out, int out_size, void* d_ws, size_t ws_size,
                              hipStream_t stream) {
    const float* X = (const float*)d_in[0];
    const int* tgt = (const int*)d_in[1];
    float* out = (float*)d_out;

    float* f = (float*)d_ws;
    int*   hist     = (int*)f;                 // [0,256)
    float* S_class  = f + 256;                 // [256,512)
    int*   coffset  = (int*)(f + 512);         // [512,768)
    float* rowsum   = f + 768;                 // [768,896)
    int*   done     = (int*)(f + 896);         // 1 int
    float* bsum     = f + 1024;                // [1024,1536)  512 entries
    float* blocksum = f + 1536;                // [1536,1568)
    int*   cstart   = (int*)(f + 1600);        // [1600,1857)
    float* sq       = f + 2048;                // [2048,10240)
    float* upk      = f + 10240;               // [10240,18432)
    unsigned int* Xbf = (unsigned int*)(f + 18432);   // 2 MB: [18432,542720)
    float4* partial = (float4*)(f + 542720);   // ns*8192 float4

    int ns = 8;   // slice == XCD id
    while (ns > 2 && ws_size < ((size_t)542720 + (size_t)ns * NROWS * 4) * sizeof(float))
        ns >>= 1;
    int shift = (ns == 8) ? 3 : (ns == 4) ? 2 : 1;
    int tiles = 64 / ns;

    histscan_kernel<<<1, 1024, 0, stream>>>(tgt, hist, cstart, coffset,
                                            S_class, rowsum, done);
    prep_kernel<<<512, 256, 0, stream>>>(X, tgt, sq, upk, Xbf,
                                         coffset, S_class, bsum, rowsum);
    dist_kernel<<<64 * ns, 256, 0, stream>>>((const unsigned short*)Xbf,
                                             upk, cstart, partial,
                                             ns - 1, shift, tiles);
    combine_kernel<<<32, 256, 0, stream>>>(sq, upk, Xbf, hist, S_class, bsum,
                                           rowsum, partial, blocksum, done, out, ns);
}